// Round 9
// baseline (948.015 us; speedup 1.0000x reference)
//
#include <hip/hip_runtime.h>
#include <cstddef>
#include <cstdint>

// Problem constants (from reference): B=256, T=512, I=128, H=64, 4H=256.
#define NB 256
#define NT 512
#define H4 256

typedef float v2f __attribute__((ext_vector_type(2)));
typedef _Float16 v2h __attribute__((ext_vector_type(2)));

// Quad-lane exchange via DPP quad_perm (pure VALU, no LDS pipe):
// xor1: perm(1,0,3,2)=0xB1 ; xor2: perm(2,3,0,1)=0x4E
__device__ __forceinline__ float dpp_xor1(float x) {
    int r = __builtin_amdgcn_update_dpp(0, __float_as_int(x), 0xB1, 0xF, 0xF, true);
    return __int_as_float(r);
}
__device__ __forceinline__ float dpp_xor2(float x) {
    int r = __builtin_amdgcn_update_dpp(0, __float_as_int(x), 0x4E, 0xF, 0xF, true);
    return __int_as_float(r);
}

// returns x[m] for runtime m (2-level cndmask)
__device__ __forceinline__ float sel4(float x0, float x1, float x2, float x3, int m) {
    float lo = (m & 1) ? x1 : x0;
    float hi = (m & 1) ? x3 : x2;
    return (m & 2) ? hi : lo;
}

// pack two f32 into f16x2 (RTN via scalar casts), stored as int
__device__ __forceinline__ int pack2h(float a, float b) {
    v2h p; p.x = (_Float16)a; p.y = (_Float16)b;
    return __builtin_bit_cast(int, p);
}
// c += dot(f16x2, f16x2) in f32 — clang folds to v_fma_mix_f32 pairs
__device__ __forceinline__ float dot2acc(int wb, int xb, float c) {
    v2h w = __builtin_bit_cast(v2h, wb);
    v2h x = __builtin_bit_cast(v2h, xb);
    c = __builtin_fmaf((float)w.x, (float)x.x, c);
    c = __builtin_fmaf((float)w.y, (float)x.y, c);
    return c;
}

// ---------------------------------------------------------------------------
// Transpose W [256, K] -> Wt [K, 256] (tiny, once; layer-0 GEMM only)
// ---------------------------------------------------------------------------
__global__ void transpose_w(const float* __restrict__ W, float* __restrict__ Wt, int K) {
    int idx = blockIdx.x * 256 + threadIdx.x;
    if (idx < 256 * K) {
        int n = idx / K, k = idx - n * K;
        Wt[k * 256 + n] = W[idx];
    }
}

// ---------------------------------------------------------------------------
// Input-projection GEMM for layer 0 only (K=128). Unchanged.
// ---------------------------------------------------------------------------
template <int K>
__global__ __launch_bounds__(256) void gemm_xp(
    const float* __restrict__ X, const float* __restrict__ Wt,
    const float* __restrict__ b1, const float* __restrict__ b2,
    float* __restrict__ XP)
{
    constexpr int TM = 64;
    constexpr int KC = 16;
    __shared__ __align__(16) float xT[K][TM + 4];
    __shared__ __align__(16) float wc[KC][256];
    const int m0 = blockIdx.x * TM;
    const int t  = threadIdx.x;
    const int cg = (t & 63) * 4;
    const int rg = (t >> 6) * 16;

    for (int idx = t; idx < TM * K; idx += 256) {
        int r = idx / K, k = idx - r * K;
        xT[k][r] = X[(size_t)(m0 + r) * K + k];
    }

    float acc[16][4];
    #pragma unroll
    for (int i = 0; i < 16; ++i)
        #pragma unroll
        for (int j = 0; j < 4; ++j) acc[i][j] = 0.f;

    for (int kc = 0; kc < K; kc += KC) {
        __syncthreads();
        #pragma unroll
        for (int i = 0; i < 4; ++i) {
            int e4 = (t + i * 256) * 4;
            int k = e4 >> 8, n = e4 & 255;
            *(float4*)&wc[k][n] = *(const float4*)&Wt[(size_t)(kc + k) * 256 + n];
        }
        __syncthreads();
        #pragma unroll
        for (int k = 0; k < KC; ++k) {
            float4 w = *(const float4*)&wc[k][cg];
            float xr[16];
            #pragma unroll
            for (int q = 0; q < 4; ++q)
                *(float4*)&xr[q * 4] = *(const float4*)&xT[kc + k][rg + q * 4];
            #pragma unroll
            for (int rr = 0; rr < 16; ++rr) {
                acc[rr][0] += xr[rr] * w.x;
                acc[rr][1] += xr[rr] * w.y;
                acc[rr][2] += xr[rr] * w.z;
                acc[rr][3] += xr[rr] * w.w;
            }
        }
    }

    float bias[4];
    #pragma unroll
    for (int j = 0; j < 4; ++j) bias[j] = b1[cg + j] + b2[cg + j];
    #pragma unroll
    for (int rr = 0; rr < 16; ++rr) {
        float4 o;
        o.x = acc[rr][0] + bias[0];
        o.y = acc[rr][1] + bias[1];
        o.z = acc[rr][2] + bias[2];
        o.w = acc[rr][3] + bias[3];
        *(float4*)&XP[(size_t)(m0 + rg + rr) * 256 + cg] = o;
    }
}

// ---------------------------------------------------------------------------
// Fused 3-layer wavefront-pipelined LSTM scan, f16-weight edition.
// vs round 8: the 128-f32/lane weight file (which the compiler refused to
// keep register-resident at its 84-VGPR heuristic target, re-loading it from
// scratch/L2 every step) is packed to f16x2 (64 int regs for wg+wi), h is
// exchanged through LDS as _Float16 (h-slice = 8 regs, ds-reads halved), and
// every packed weight reg is PINNED with an empty asm so the compiler cannot
// sink/rematerialize the loads into the loop. Working set now fits ~92 regs.
// Matvecs use (float)(_Float16) casts + fmaf -> v_fma_mix_f32.
// ---------------------------------------------------------------------------
__global__ __attribute__((amdgpu_flat_work_group_size(768, 768)))
__attribute__((amdgpu_waves_per_eu(3, 3)))
void lstm_fused3(
    const float* __restrict__ xp,    // [B*T, 256] layer-0 xp (incl. both biases)
    const float* __restrict__ Whh0,
    const float* __restrict__ Wih1, const float* __restrict__ Whh1,
    const float* __restrict__ bi1, const float* __restrict__ bh1,
    const float* __restrict__ Wih2, const float* __restrict__ Whh2,
    const float* __restrict__ bi2, const float* __restrict__ bh2,
    float* __restrict__ hl)          // [B, 64] layer-2 h at t = NT-1
{
    const int tid = threadIdx.x;
    const int b = blockIdx.x;
    const int L = tid >> 8;            // 0,1,2 (4 waves each)
    const int t256 = tid & 255;
    const int ks = t256 & 3;
    const int u = t256 >> 2;           // 0..63

    __shared__ __align__(16) _Float16 hb[3][2][64];   // 768 B

    // Recurrent weights, XOR-permuted: slot j = gate (ks^j), k-slice ks.
    // Packed f16x2 in int regs.
    const float* Whh = (L == 0) ? Whh0 : (L == 1) ? Whh1 : Whh2;
    int wgb[4][8];
    #pragma unroll
    for (int j = 0; j < 4; ++j) {
        const float* Wr = Whh + (size_t)(((ks ^ j) * 64) + u) * 64 + ks * 16;
        #pragma unroll
        for (int q = 0; q < 8; ++q) wgb[j][q] = pack2h(Wr[2 * q], Wr[2 * q + 1]);
    }
    // Input-projection weights + bias for layers 1,2
    int wib[4][8];
    float bsum = 0.f;
    if (L > 0) {
        const float* Wih = (L == 1) ? Wih1 : Wih2;
        #pragma unroll
        for (int j = 0; j < 4; ++j) {
            const float* Wr = Wih + (size_t)(((ks ^ j) * 64) + u) * 64 + ks * 16;
            #pragma unroll
            for (int q = 0; q < 8; ++q) wib[j][q] = pack2h(Wr[2 * q], Wr[2 * q + 1]);
        }
        const float* bi = (L == 1) ? bi1 : bi2;
        const float* bh = (L == 1) ? bh1 : bh2;
        bsum = bi[ks * 64 + u] + bh[ks * 64 + u];
        // pin wi regs: load results become opaque -> cannot be sunk into loop
        #pragma unroll
        for (int j = 0; j < 4; ++j)
            #pragma unroll
            for (int q = 0; q < 8; ++q) asm volatile("" : "+v"(wib[j][q]));
    }
    // pin wg regs
    #pragma unroll
    for (int j = 0; j < 4; ++j)
        #pragma unroll
        for (int q = 0; q < 8; ++q) asm volatile("" : "+v"(wgb[j][q]));

    // Per-lane activation constants (gate 2 = tanh)
    const float LOG2E = 1.4426950408889634f;
    const float M = (ks == 2) ? (2.f * LOG2E) : LOG2E;
    const float A = (ks == 2) ? 2.f : 1.f;
    const float Bc = (ks == 2) ? -1.f : 0.f;

    if (tid < 192) ((int*)hb)[tid] = 0;   // zero all h buffers (768 B)

    // layer-0 xp prefetch ring (depth 4)
    const float* xpb = xp + (size_t)b * NT * H4 + (ks * 64 + u);
    float xr[4];
    if (L == 0) {
        #pragma unroll
        for (int d = 0; d < 4; ++d) xr[d] = xpb[(size_t)d * H4];
    }

    asm volatile("s_waitcnt lgkmcnt(0)" ::: "memory");
    __builtin_amdgcn_s_barrier();
    __builtin_amdgcn_sched_barrier(0);

    float c = 0.f, h = 0.f;
    const bool writer = (ks == 0);

    for (int s = 0; s < NT + 2; ++s) {
        const int t = s - L;
        const bool active = (t >= 0) && (t < NT);
        if (active) {
            // ---- own-h matvec over k-slice ks (16 f16 = 8 int reads) ----
            const int* hv = (const int*)&hb[L][t & 1][ks * 16];
            int hh[8];
            #pragma unroll
            for (int q = 0; q < 8; ++q) hh[q] = hv[q];
            float p[4];
            #pragma unroll
            for (int j = 0; j < 4; ++j) {
                float a0 = 0.f, a1 = 0.f;
                #pragma unroll
                for (int q = 0; q < 8; q += 2) {
                    a0 = dot2acc(wgb[j][q], hh[q], a0);
                    a1 = dot2acc(wgb[j][q + 1], hh[q + 1], a1);
                }
                p[j] = a0 + a1;
            }

            float xc;
            if (L == 0) {
                xc = xr[t & 3];
                int tn = t + 4; if (tn > NT - 1) tn = NT - 1;
                xr[t & 3] = xpb[(size_t)tn * H4];     // fire-and-forget refill
            } else {
                // ---- fused input projection: h^{L-1}_t slice ----
                const int* gv = (const int*)&hb[L - 1][(t + 1) & 1][ks * 16];
                int gg[8];
                #pragma unroll
                for (int q = 0; q < 8; ++q) gg[q] = gv[q];
                #pragma unroll
                for (int j = 0; j < 4; ++j) {
                    float a0 = 0.f, a1 = 0.f;
                    #pragma unroll
                    for (int q = 0; q < 8; q += 2) {
                        a0 = dot2acc(wib[j][q], gg[q], a0);
                        a1 = dot2acc(wib[j][q + 1], gg[q + 1], a1);
                    }
                    p[j] += a0 + a1;
                }
                xc = bsum;
            }

            // ---- reduce-scatter: full pre-activation of OWN gate ks ----
            float S = p[0] + dpp_xor1(p[1]);
            float t3 = dpp_xor2(dpp_xor1(p[3]));
            S += dpp_xor2(p[2]) + t3;
            float pre = S + xc;

            // ---- single branchless activation chain ----
            float e = __builtin_amdgcn_exp2f(-(pre * M));
            float y = __builtin_amdgcn_rcpf(1.f + e);
            float act = __builtin_fmaf(A, y, Bc);

            // ---- allgather + gate extraction ----
            float a1g = dpp_xor1(act);
            float a2g = dpp_xor2(act);
            float a3g = dpp_xor2(a1g);
            float ig = (ks & 1) ? (a1g * a3g) : (act * a2g);   // i*g
            float fv = sel4(a1g, act, a3g, a2g, ks);           // f
            float ov = sel4(a3g, a2g, a1g, act, ks);           // o

            // ---- cell update (redundant x4, identical bits) ----
            c = __builtin_fmaf(fv, c, ig);
            float e2 = __builtin_amdgcn_exp2f(-(c * (2.f * LOG2E)));
            float y2 = __builtin_amdgcn_rcpf(1.f + e2);
            float th = __builtin_fmaf(2.f, y2, -1.f);
            h = ov * th;

            if (writer) {
                hb[L][(t + 1) & 1][u] = (_Float16)h;   // parity no reader touches
                if (L == 2 && t == NT - 1) hl[(size_t)b * 64 + u] = h;
            }
        }
        asm volatile("s_waitcnt lgkmcnt(0)" ::: "memory");
        __builtin_amdgcn_s_barrier();
        __builtin_amdgcn_sched_barrier(0);
    }
}

// ---------------------------------------------------------------------------
// Final linear: out[b][o] = b_out[o] + sum_j h_last[b][j] * W_out[o][j]
// ---------------------------------------------------------------------------
__global__ __launch_bounds__(256) void final_linear(
    const float* __restrict__ hl,    // [256, 64]
    const float* __restrict__ Wout,  // [2, 64]
    const float* __restrict__ bout,  // [2]
    float* __restrict__ out)         // [256, 2]
{
    __shared__ float w[128];
    int t = threadIdx.x;
    if (t < 128) w[t] = Wout[t];
    __syncthreads();
    const float* h = hl + (size_t)t * 64;
    float a0 = bout[0], a1 = bout[1];
    #pragma unroll 8
    for (int j = 0; j < 64; ++j) {
        float hv = h[j];
        a0 += hv * w[j];
        a1 += hv * w[64 + j];
    }
    out[t * 2 + 0] = a0;
    out[t * 2 + 1] = a1;
}

// ---------------------------------------------------------------------------
extern "C" void kernel_launch(void* const* d_in, const int* in_sizes, int n_in,
                              void* d_out, int out_size, void* d_ws, size_t ws_size,
                              hipStream_t stream)
{
    const float* x     = (const float*)d_in[0];
    const float* W_ih0 = (const float*)d_in[1];
    const float* W_hh0 = (const float*)d_in[2];
    const float* b_ih0 = (const float*)d_in[3];
    const float* b_hh0 = (const float*)d_in[4];
    const float* W_ih1 = (const float*)d_in[5];
    const float* W_hh1 = (const float*)d_in[6];
    const float* b_ih1 = (const float*)d_in[7];
    const float* b_hh1 = (const float*)d_in[8];
    const float* W_ih2 = (const float*)d_in[9];
    const float* W_hh2 = (const float*)d_in[10];
    const float* b_ih2 = (const float*)d_in[11];
    const float* b_hh2 = (const float*)d_in[12];
    const float* W_out = (const float*)d_in[13];
    const float* b_out = (const float*)d_in[14];
    float* out = (float*)d_out;

    const size_t M = (size_t)NB * NT;                  // 131072
    const size_t XP_BYTES  = M * H4 * sizeof(float);   // 128 MiB
    const size_t WT0_BYTES = 128 * 256 * sizeof(float);
    const size_t HL_BYTES  = NB * 64 * sizeof(float);
    if (ws_size < XP_BYTES + WT0_BYTES + HL_BYTES)
        return;

    char* ws = (char*)d_ws;
    float* XP  = (float*)ws;
    float* WT0 = (float*)(ws + XP_BYTES);
    float* HL  = WT0 + 128 * 256;

    // Layer-0 input projection (parallel GEMM) — layers 1,2 are fused.
    transpose_w<<<128, 256, 0, stream>>>(W_ih0, WT0, 128);
    gemm_xp<128><<<(int)(M / 64), 256, 0, stream>>>(x, WT0, b_ih0, b_hh0, XP);

    // Fused 3-layer pipelined scan.
    lstm_fused3<<<NB, 768, 0, stream>>>(XP, W_hh0,
                                        W_ih1, W_hh1, b_ih1, b_hh1,
                                        W_ih2, W_hh2, b_ih2, b_hh2, HL);

    // Final projection.
    final_linear<<<1, 256, 0, stream>>>(HL, W_out, b_out, out);
}

// Round 10
// 747.423 us; speedup vs baseline: 1.2684x; 1.2684x over previous
//
#include <hip/hip_runtime.h>
#include <cstddef>
#include <cstdint>

// Problem constants (from reference): B=256, T=512, I=128, H=64, 4H=256.
#define NB 256
#define NT 512
#define H4 256

typedef _Float16 v2h __attribute__((ext_vector_type(2)));

// Quad-lane exchange via DPP quad_perm (pure VALU):
// xor1: perm(1,0,3,2)=0xB1 ; xor2: perm(2,3,0,1)=0x4E
__device__ __forceinline__ float dpp_xor1(float x) {
    int r = __builtin_amdgcn_update_dpp(0, __float_as_int(x), 0xB1, 0xF, 0xF, true);
    return __int_as_float(r);
}
__device__ __forceinline__ float dpp_xor2(float x) {
    int r = __builtin_amdgcn_update_dpp(0, __float_as_int(x), 0x4E, 0xF, 0xF, true);
    return __int_as_float(r);
}
__device__ __forceinline__ float sel4(float x0, float x1, float x2, float x3, int m) {
    float lo = (m & 1) ? x1 : x0;
    float hi = (m & 1) ? x3 : x2;
    return (m & 2) ? hi : lo;
}
__device__ __forceinline__ int pack2h(float a, float b) {
    v2h p; p.x = (_Float16)a; p.y = (_Float16)b;
    return __builtin_bit_cast(int, p);
}
#if __has_builtin(__builtin_amdgcn_fdot2)
__device__ __forceinline__ float dot2acc(int wb, int xb, float c) {
    return __builtin_amdgcn_fdot2(__builtin_bit_cast(v2h, wb),
                                  __builtin_bit_cast(v2h, xb), c, false);
}
#else
__device__ __forceinline__ float dot2acc(int wb, int xb, float c) {
    v2h w = __builtin_bit_cast(v2h, wb);
    v2h x = __builtin_bit_cast(v2h, xb);
    c = __builtin_fmaf((float)w.x, (float)x.x, c);
    c = __builtin_fmaf((float)w.y, (float)x.y, c);
    return c;
}
#endif

// Load XOR-permuted quad weights: slot j = row (ks^j)*64+u, k-slice ks*16..+16
__device__ __forceinline__ void load_wq(const float* W, int ks, int u, int wq[4][8]) {
    #pragma unroll
    for (int j = 0; j < 4; ++j) {
        const float* Wr = W + (size_t)(((ks ^ j) * 64) + u) * 64 + ks * 16;
        #pragma unroll
        for (int q = 0; q < 8; ++q) wq[j][q] = pack2h(Wr[2 * q], Wr[2 * q + 1]);
    }
}
// partial dots over own slice for 4 slots + DPP reduce-scatter -> own gate's full sum
__device__ __forceinline__ float quad_matvec_reduce(const int wq[4][8], const int hh[8]) {
    float p[4];
    #pragma unroll
    for (int j = 0; j < 4; ++j) {
        float a0 = 0.f, a1 = 0.f;
        #pragma unroll
        for (int q = 0; q < 8; q += 2) {
            a0 = dot2acc(wq[j][q], hh[q], a0);
            a1 = dot2acc(wq[j][q + 1], hh[q + 1], a1);
        }
        p[j] = a0 + a1;
    }
    float S = p[0] + dpp_xor1(p[1]);
    S += dpp_xor2(p[2]) + dpp_xor2(dpp_xor1(p[3]));
    return S;
}

// ---------------------------------------------------------------------------
// Transpose W [256, K] -> Wt [K, 256] (layer-0 GEMM only)
// ---------------------------------------------------------------------------
__global__ void transpose_w(const float* __restrict__ W, float* __restrict__ Wt, int K) {
    int idx = blockIdx.x * 256 + threadIdx.x;
    if (idx < 256 * K) {
        int n = idx / K, k = idx - n * K;
        Wt[k * 256 + n] = W[idx];
    }
}

// ---------------------------------------------------------------------------
// Input-projection GEMM for layer 0 only (K=128). Unchanged (proven).
// ---------------------------------------------------------------------------
template <int K>
__global__ __launch_bounds__(256) void gemm_xp(
    const float* __restrict__ X, const float* __restrict__ Wt,
    const float* __restrict__ b1, const float* __restrict__ b2,
    float* __restrict__ XP)
{
    constexpr int TM = 64;
    constexpr int KC = 16;
    __shared__ __align__(16) float xT[K][TM + 4];
    __shared__ __align__(16) float wc[KC][256];
    const int m0 = blockIdx.x * TM;
    const int t  = threadIdx.x;
    const int cg = (t & 63) * 4;
    const int rg = (t >> 6) * 16;

    for (int idx = t; idx < TM * K; idx += 256) {
        int r = idx / K, k = idx - r * K;
        xT[k][r] = X[(size_t)(m0 + r) * K + k];
    }

    float acc[16][4];
    #pragma unroll
    for (int i = 0; i < 16; ++i)
        #pragma unroll
        for (int j = 0; j < 4; ++j) acc[i][j] = 0.f;

    for (int kc = 0; kc < K; kc += KC) {
        __syncthreads();
        #pragma unroll
        for (int i = 0; i < 4; ++i) {
            int e4 = (t + i * 256) * 4;
            int k = e4 >> 8, n = e4 & 255;
            *(float4*)&wc[k][n] = *(const float4*)&Wt[(size_t)(kc + k) * 256 + n];
        }
        __syncthreads();
        #pragma unroll
        for (int k = 0; k < KC; ++k) {
            float4 w = *(const float4*)&wc[k][cg];
            float xr[16];
            #pragma unroll
            for (int q = 0; q < 4; ++q)
                *(float4*)&xr[q * 4] = *(const float4*)&xT[kc + k][rg + q * 4];
            #pragma unroll
            for (int rr = 0; rr < 16; ++rr) {
                acc[rr][0] += xr[rr] * w.x;
                acc[rr][1] += xr[rr] * w.y;
                acc[rr][2] += xr[rr] * w.z;
                acc[rr][3] += xr[rr] * w.w;
            }
        }
    }

    float bias[4];
    #pragma unroll
    for (int j = 0; j < 4; ++j) bias[j] = b1[cg + j] + b2[cg + j];
    #pragma unroll
    for (int rr = 0; rr < 16; ++rr) {
        float4 o;
        o.x = acc[rr][0] + bias[0];
        o.y = acc[rr][1] + bias[1];
        o.z = acc[rr][2] + bias[2];
        o.w = acc[rr][3] + bias[3];
        *(float4*)&XP[(size_t)(m0 + rg + rr) * 256 + cg] = o;
    }
}

// ---------------------------------------------------------------------------
// Pipelined 3-layer LSTM, two blocks per batch element:
//  block b      (isL1): [R0-quad | I1-quad | R1-quad]  (12 waves, 768 thr)
//  block NB+b   (isL2): [I2-quad | R2-quad | idle   ]
// All roles hold exactly 32 packed-f16 weight regs (XOR-quad layout) -> every
// wave fits the allocator's ~64-84 VGPR budget: no sinking, no spill (the
// failure mode of rounds 6-9). I-waves compute the next layer's input
// projection OFF the recurrent critical chain. h0->I1 via LDS; h1->I2 via a
// global f16 stream gated by a per-batch progress flag (device-scope
// release/acquire every 8 steps). Forward-only flags => no deadlock even
// without co-residency.
// ---------------------------------------------------------------------------
__global__ __launch_bounds__(768) void lstm_pipe(
    const float* __restrict__ xp,    // [B*T, 256] layer-0 xp (incl. biases)
    const float* __restrict__ Whh0,
    const float* __restrict__ Wih1, const float* __restrict__ Whh1,
    const float* __restrict__ bi1, const float* __restrict__ bh1,
    const float* __restrict__ Wih2, const float* __restrict__ Whh2,
    const float* __restrict__ bi2, const float* __restrict__ bh2,
    _Float16* __restrict__ h1h,      // [B*T*64] f16 layer-1 h stream
    float* __restrict__ hl,          // [B*64] layer-2 final h
    int* __restrict__ prog)          // [B] progress flags (memset 0 per call)
{
    const int tid = threadIdx.x;
    const bool isL1 = (blockIdx.x < NB);
    const int b = isL1 ? blockIdx.x : (blockIdx.x - NB);
    const int GA = tid >> 8;           // wave-quad id: 0,1,2
    const int t256 = tid & 255;
    const int ks = t256 & 3;
    const int u = t256 >> 2;           // 0..63

    const bool roleRF = isL1 && GA == 0;                       // layer-0 scan
    const bool roleI  = (isL1 && GA == 1) || (!isL1 && GA == 0); // input proj
    const bool roleRS = (isL1 && GA == 2) || (!isL1 && GA == 1); // layer-1/2 scan

    __shared__ __align__(16) _Float16 hbA[2][64];   // layer-0 h (L1 blocks)
    __shared__ __align__(16) _Float16 hbB[2][64];   // layer-1/2 h (per block)
    __shared__ __align__(16) float xq[2][256];      // xin ring

    int wq[4][8];
    float bsum = 0.f;
    if (roleRF) load_wq(Whh0, ks, u, wq);
    if (roleI) {
        load_wq(isL1 ? Wih1 : Wih2, ks, u, wq);
        bsum = (isL1 ? bi1 : bi2)[ks * 64 + u] + (isL1 ? bh1 : bh2)[ks * 64 + u];
    }
    if (roleRS) load_wq(isL1 ? Whh1 : Whh2, ks, u, wq);

    // per-lane activation constants (gate 2 = tanh)
    const float LOG2E = 1.4426950408889634f;
    const float Mact = (ks == 2) ? (2.f * LOG2E) : LOG2E;
    const float Aact = (ks == 2) ? 2.f : 1.f;
    const float Bact = (ks == 2) ? -1.f : 0.f;

    if (tid < 64) {
        hbA[0][tid] = (_Float16)0.f; hbA[1][tid] = (_Float16)0.f;
        hbB[0][tid] = (_Float16)0.f; hbB[1][tid] = (_Float16)0.f;
    }
    if (tid < 512) ((float*)xq)[tid] = 0.f;

    // layer-0 xp prefetch ring (depth 4)
    const float* xpb = xp + (size_t)b * NT * H4 + (ks * 64 + u);
    float xr[4];
    if (roleRF) {
        #pragma unroll
        for (int d = 0; d < 4; ++d) xr[d] = xpb[(size_t)d * H4];
    }

    asm volatile("s_waitcnt lgkmcnt(0)" ::: "memory");
    __builtin_amdgcn_s_barrier();
    __builtin_amdgcn_sched_barrier(0);

    float c = 0.f, h = 0.f;
    int seen = 0;
    const bool writer = (ks == 0);

    for (int s = 0; s < NT + 2; ++s) {
        // publish progress for h1 completed through t = s-3 (stores drained
        // by R1's vmcnt(0) before last barrier)
        if (isL1 && tid == 512) {
            int tp = s - 3;
            if (tp >= 0 && (tp & 7) == 7 && tp < NT)
                __hip_atomic_store(prog + b, tp + 1, __ATOMIC_RELEASE,
                                   __HIP_MEMORY_SCOPE_AGENT);
        }

        if (roleRF) {
            const int t = s;
            if (t < NT) {
                int hh[8];
                const int* hv = (const int*)&hbA[t & 1][ks * 16];
                #pragma unroll
                for (int q = 0; q < 8; ++q) hh[q] = hv[q];
                float S = quad_matvec_reduce(wq, hh);
                float xc = xr[t & 3];
                { int tn = t + 4; if (tn > NT - 1) tn = NT - 1;
                  xr[t & 3] = xpb[(size_t)tn * H4]; }
                float pre = S + xc;
                float e = __builtin_amdgcn_exp2f(-(pre * Mact));
                float y = __builtin_amdgcn_rcpf(1.f + e);
                float act = __builtin_fmaf(Aact, y, Bact);
                float a1g = dpp_xor1(act), a2g = dpp_xor2(act), a3g = dpp_xor2(a1g);
                float ig = (ks & 1) ? (a1g * a3g) : (act * a2g);
                float fv = sel4(a1g, act, a3g, a2g, ks);
                float ov = sel4(a3g, a2g, a1g, act, ks);
                c = __builtin_fmaf(fv, c, ig);
                float e2 = __builtin_amdgcn_exp2f(-(c * (2.f * LOG2E)));
                float y2 = __builtin_amdgcn_rcpf(1.f + e2);
                h = ov * __builtin_fmaf(2.f, y2, -1.f);
                if (writer) hbA[(t + 1) & 1][u] = (_Float16)h;
            }
        } else if (roleI) {
            // produce xin[s-1] into xq[(s-1)&1]
            if (s >= 1 && s <= NT) {
                const int tsrc = s - 1;
                int hh[8];
                if (isL1) {
                    const int* hv = (const int*)&hbA[s & 1][ks * 16];
                    #pragma unroll
                    for (int q = 0; q < 8; ++q) hh[q] = hv[q];
                } else {
                    if (seen < s) {
                        int sv = seen;
                        if ((t256 & 63) == 0) {
                            while ((sv = __hip_atomic_fetch_add(prog + b, 0,
                                        __ATOMIC_RELAXED, __HIP_MEMORY_SCOPE_AGENT)) < s) {}
                        }
                        sv = __builtin_amdgcn_readfirstlane(sv);
                        __builtin_amdgcn_fence(__ATOMIC_ACQUIRE, "agent");
                        seen = sv;
                    }
                    const int* gv = (const int*)(h1h + ((size_t)b * NT + tsrc) * 64 + ks * 16);
                    #pragma unroll
                    for (int q = 0; q < 8; ++q) hh[q] = gv[q];
                }
                float S = quad_matvec_reduce(wq, hh);
                xq[tsrc & 1][ks * 64 + u] = S + bsum;
            }
        } else if (roleRS) {
            const int t = s - 2;
            if (t >= 0 && t < NT) {
                int hh[8];
                const int* hv = (const int*)&hbB[t & 1][ks * 16];
                #pragma unroll
                for (int q = 0; q < 8; ++q) hh[q] = hv[q];
                float S = quad_matvec_reduce(wq, hh);
                float xc = xq[t & 1][ks * 64 + u];
                float pre = S + xc;
                float e = __builtin_amdgcn_exp2f(-(pre * Mact));
                float y = __builtin_amdgcn_rcpf(1.f + e);
                float act = __builtin_fmaf(Aact, y, Bact);
                float a1g = dpp_xor1(act), a2g = dpp_xor2(act), a3g = dpp_xor2(a1g);
                float ig = (ks & 1) ? (a1g * a3g) : (act * a2g);
                float fv = sel4(a1g, act, a3g, a2g, ks);
                float ov = sel4(a3g, a2g, a1g, act, ks);
                c = __builtin_fmaf(fv, c, ig);
                float e2 = __builtin_amdgcn_exp2f(-(c * (2.f * LOG2E)));
                float y2 = __builtin_amdgcn_rcpf(1.f + e2);
                h = ov * __builtin_fmaf(2.f, y2, -1.f);
                if (writer) {
                    hbB[(t + 1) & 1][u] = (_Float16)h;
                    if (isL1) h1h[((size_t)b * NT + t) * 64 + u] = (_Float16)h;
                    else if (t == NT - 1) hl[(size_t)b * 64 + u] = h;
                }
                // drain h1 stores before the barrier at publish boundaries
                if (isL1 && (((t & 7) == 7) || t == NT - 1))
                    asm volatile("s_waitcnt vmcnt(0)" ::: "memory");
            }
        }
        asm volatile("s_waitcnt lgkmcnt(0)" ::: "memory");
        __builtin_amdgcn_s_barrier();
        __builtin_amdgcn_sched_barrier(0);
    }
    if (isL1 && tid == 512)
        __hip_atomic_store(prog + b, NT, __ATOMIC_RELEASE, __HIP_MEMORY_SCOPE_AGENT);
}

// ---------------------------------------------------------------------------
// Final linear: out[b][o] = b_out[o] + sum_j h_last[b][j] * W_out[o][j]
// ---------------------------------------------------------------------------
__global__ __launch_bounds__(256) void final_linear(
    const float* __restrict__ hlv, const float* __restrict__ Wout,
    const float* __restrict__ bout, float* __restrict__ out)
{
    __shared__ float w[128];
    int t = threadIdx.x;
    if (t < 128) w[t] = Wout[t];
    __syncthreads();
    const float* h = hlv + (size_t)t * 64;
    float a0 = bout[0], a1 = bout[1];
    #pragma unroll 8
    for (int j = 0; j < 64; ++j) {
        float hv = h[j];
        a0 += hv * w[j];
        a1 += hv * w[64 + j];
    }
    out[t * 2 + 0] = a0;
    out[t * 2 + 1] = a1;
}

// ---------------------------------------------------------------------------
extern "C" void kernel_launch(void* const* d_in, const int* in_sizes, int n_in,
                              void* d_out, int out_size, void* d_ws, size_t ws_size,
                              hipStream_t stream)
{
    const float* x     = (const float*)d_in[0];
    const float* W_ih0 = (const float*)d_in[1];
    const float* W_hh0 = (const float*)d_in[2];
    const float* b_ih0 = (const float*)d_in[3];
    const float* b_hh0 = (const float*)d_in[4];
    const float* W_ih1 = (const float*)d_in[5];
    const float* W_hh1 = (const float*)d_in[6];
    const float* b_ih1 = (const float*)d_in[7];
    const float* b_hh1 = (const float*)d_in[8];
    const float* W_ih2 = (const float*)d_in[9];
    const float* W_hh2 = (const float*)d_in[10];
    const float* b_ih2 = (const float*)d_in[11];
    const float* b_hh2 = (const float*)d_in[12];
    const float* W_out = (const float*)d_in[13];
    const float* b_out = (const float*)d_in[14];
    float* out = (float*)d_out;

    const size_t M = (size_t)NB * NT;                    // 131072
    const size_t XP_BYTES  = M * H4 * sizeof(float);     // 128 MiB
    const size_t WT0_BYTES = 128 * 256 * sizeof(float);
    const size_t H1H_BYTES = M * 64 * sizeof(_Float16);  // 16 MiB
    const size_t HL_BYTES  = NB * 64 * sizeof(float);
    const size_t PROG_BYTES = NB * sizeof(int);
    if (ws_size < XP_BYTES + WT0_BYTES + H1H_BYTES + HL_BYTES + PROG_BYTES)
        return;

    char* ws = (char*)d_ws;
    float*     XP   = (float*)ws;
    float*     WT0  = (float*)(ws + XP_BYTES);
    _Float16*  H1H  = (_Float16*)(ws + XP_BYTES + WT0_BYTES);
    float*     HL   = (float*)(ws + XP_BYTES + WT0_BYTES + H1H_BYTES);
    int*       PROG = (int*)(ws + XP_BYTES + WT0_BYTES + H1H_BYTES + HL_BYTES);

    // reset flags every call (graph replays!)
    hipMemsetAsync(PROG, 0, PROG_BYTES, stream);

    // Layer-0 input projection (parallel GEMM); layers 1,2 fused in pipe.
    transpose_w<<<128, 256, 0, stream>>>(W_ih0, WT0, 128);
    gemm_xp<128><<<(int)(M / 64), 256, 0, stream>>>(x, WT0, b_ih0, b_hh0, XP);

    // Pipelined scan: blocks [0,NB) = L1-blocks, [NB,2NB) = L2-blocks.
    lstm_pipe<<<2 * NB, 768, 0, stream>>>(XP, W_hh0,
                                          W_ih1, W_hh1, b_ih1, b_hh1,
                                          W_ih2, W_hh2, b_ih2, b_hh2,
                                          H1H, HL, PROG);

    final_linear<<<1, 256, 0, stream>>>(HL, W_out, b_out, out);
}

// Round 11
// 710.535 us; speedup vs baseline: 1.3342x; 1.0519x over previous
//
#include <hip/hip_runtime.h>
#include <cstddef>
#include <cstdint>

// Problem constants: B=256, T=512, I=128, H=64, 4H=256.
#define NB 256
#define NT 512
#define H4 256
#define CH 32              // chunk length (timesteps)
#define NC (NT / CH)       // 16 chunks
#define NSTAGE (NC + 5)    // 21 pipeline stages

typedef float v2f __attribute__((ext_vector_type(2)));

// DPP quad_perm lane exchange (pure VALU): xor1=0xB1, xor2=0x4E
__device__ __forceinline__ float dpp_xor1(float x) {
    int r = __builtin_amdgcn_update_dpp(0, __float_as_int(x), 0xB1, 0xF, 0xF, true);
    return __int_as_float(r);
}
__device__ __forceinline__ float dpp_xor2(float x) {
    int r = __builtin_amdgcn_update_dpp(0, __float_as_int(x), 0x4E, 0xF, 0xF, true);
    return __int_as_float(r);
}
__device__ __forceinline__ float sel4(float x0, float x1, float x2, float x3, int m) {
    float lo = (m & 1) ? x1 : x0;
    float hi = (m & 1) ? x3 : x2;
    return (m & 2) ? hi : lo;
}

// ---------------------------------------------------------------------------
// Transpose W [256, K] -> Wt [K, 256]
// ---------------------------------------------------------------------------
__global__ void transpose_w(const float* __restrict__ W, float* __restrict__ Wt, int K) {
    int idx = blockIdx.x * 256 + threadIdx.x;
    if (idx < 256 * K) {
        int n = idx / K, k = idx - n * K;
        Wt[k * 256 + n] = W[idx];
    }
}

// ---------------------------------------------------------------------------
// GEMM role: one block computes XIN rows [32 x 256] for one batch's chunk.
// O[r][n] = sum_k X[r][k] * Wt[k][n] + b1[n] + b2[n]   (proven round-1 inner)
// LDS: xT[K][36] + wc[8][256]  (max 6656 floats = 26.6 KB at K=128)
// ---------------------------------------------------------------------------
template <int K>
__device__ __forceinline__ void gemm_role(
    const float* __restrict__ Xb,    // 32 contiguous rows of K
    const float* __restrict__ Wt,    // [K][256]
    const float* __restrict__ b1, const float* __restrict__ b2,
    float* __restrict__ Ob,          // 32 contiguous rows of 256
    float* smem, int t)
{
    constexpr int TM = 32, KC = 8;
    float* xT = smem;                // [K][36] (rows 144B -> 16B aligned)
    float* wc = smem + K * 36;       // [KC][256]
    const int cg = (t & 63) * 4;
    const int rg = (t >> 6) * 8;

    #pragma unroll
    for (int idx = t; idx < TM * K; idx += 256) {
        int r = idx >> (K == 128 ? 7 : 6), k2 = idx & (K - 1);
        xT[k2 * 36 + r] = Xb[idx];
    }

    float acc[8][4];
    #pragma unroll
    for (int i = 0; i < 8; ++i)
        #pragma unroll
        for (int j = 0; j < 4; ++j) acc[i][j] = 0.f;

    for (int kc = 0; kc < K; kc += KC) {
        __syncthreads();
        #pragma unroll
        for (int i = 0; i < 2; ++i) {
            int e4 = (t + i * 256) * 4;
            int kk = e4 >> 8, n = e4 & 255;
            *(float4*)&wc[kk * 256 + n] = *(const float4*)&Wt[(size_t)(kc + kk) * 256 + n];
        }
        __syncthreads();
        #pragma unroll
        for (int kk = 0; kk < KC; ++kk) {
            float4 w = *(const float4*)&wc[kk * 256 + cg];
            float xr[8];
            *(float4*)&xr[0] = *(const float4*)&xT[(kc + kk) * 36 + rg];
            *(float4*)&xr[4] = *(const float4*)&xT[(kc + kk) * 36 + rg + 4];
            #pragma unroll
            for (int rr = 0; rr < 8; ++rr) {
                acc[rr][0] += xr[rr] * w.x;
                acc[rr][1] += xr[rr] * w.y;
                acc[rr][2] += xr[rr] * w.z;
                acc[rr][3] += xr[rr] * w.w;
            }
        }
    }

    float bias[4];
    #pragma unroll
    for (int j = 0; j < 4; ++j) bias[j] = b1[cg + j] + b2[cg + j];
    #pragma unroll
    for (int rr = 0; rr < 8; ++rr) {
        float4 o;
        o.x = acc[rr][0] + bias[0];
        o.y = acc[rr][1] + bias[1];
        o.z = acc[rr][2] + bias[2];
        o.w = acc[rr][3] + bias[3];
        *(float4*)&Ob[(size_t)(rg + rr) * 256 + cg] = o;
    }
}

// ---------------------------------------------------------------------------
// Scan role: round-5 XOR-quad scan (proven 835 cyc/step, exact f32),
// chunked: seeds h/c from state, runs CH steps, stores state back.
// ---------------------------------------------------------------------------
__device__ __forceinline__ void scan_role(
    const float* __restrict__ xinb,  // ring base for (c,b), + lane col; rows *256
    const float* __restrict__ Whh,   // [256][64]
    float* __restrict__ hstr,        // ring base for (c,b) rows*64, or nullptr
    float* __restrict__ hl,          // layer-2 final h [B*64], or nullptr
    float* __restrict__ STh, float* __restrict__ STc,  // per-layer [B*64]
    int b, int c, int tid, float* smem)
{
    const int ks = tid & 3;
    const int u = tid >> 2;
    float* hbuf = smem;              // [2][64]

    // XOR-permuted per-lane weights: slot j = gate (ks^j), k-slice ks (f32, exact)
    v2f wg[4][8];
    #pragma unroll
    for (int j = 0; j < 4; ++j) {
        const v2f* Wv = (const v2f*)(Whh + (size_t)(((ks ^ j) * 64) + u) * 64 + ks * 16);
        #pragma unroll
        for (int q = 0; q < 8; ++q) wg[j][q] = Wv[q];
    }

    const float LOG2E = 1.4426950408889634f;
    const float M = (ks == 2) ? (2.f * LOG2E) : LOG2E;
    const float A = (ks == 2) ? 2.f : 1.f;
    const float Bc = (ks == 2) ? -1.f : 0.f;

    // seed state (t0 = c*CH is even -> read parity 0)
    if (tid < 64) hbuf[tid] = (c == 0) ? 0.f : STh[b * 64 + tid];
    float creg = (c == 0) ? 0.f : STc[b * 64 + u];

    asm volatile("s_waitcnt lgkmcnt(0)" ::: "memory");
    __builtin_amdgcn_s_barrier();
    __builtin_amdgcn_sched_barrier(0);

    float xr[4];
    #pragma unroll
    for (int d = 0; d < 4; ++d) xr[d] = xinb[(size_t)d * H4];

    const bool writer = (ks == 0);
    float h = 0.f;

    #pragma unroll 4
    for (int ti = 0; ti < CH; ++ti) {
        const v2f* hv = (const v2f*)&hbuf[(ti & 1) * 64 + ks * 16];
        v2f h0 = hv[0], h1 = hv[1], h2 = hv[2], h3 = hv[3];
        v2f h4 = hv[4], h5 = hv[5], h6 = hv[6], h7 = hv[7];

        float p[4];
        #pragma unroll
        for (int j = 0; j < 4; ++j) {
            v2f s0 = wg[j][0] * h0 + wg[j][2] * h2;
            v2f s1 = wg[j][1] * h1 + wg[j][3] * h3;
            s0 += wg[j][4] * h4 + wg[j][6] * h6;
            s1 += wg[j][5] * h5 + wg[j][7] * h7;
            v2f ss = s0 + s1;
            p[j] = ss.x + ss.y;
        }

        float xc = xr[ti & 3];
        { int tn = ti + 4; if (tn > CH - 1) tn = CH - 1;   // clamp in-slot
          xr[ti & 3] = xinb[(size_t)tn * H4]; }

        float S = p[0] + dpp_xor1(p[1]);
        S += dpp_xor2(p[2]) + dpp_xor2(dpp_xor1(p[3]));
        float pre = S + xc;

        float e = __builtin_amdgcn_exp2f(-(pre * M));
        float y = __builtin_amdgcn_rcpf(1.f + e);
        float act = __builtin_fmaf(A, y, Bc);

        float a1g = dpp_xor1(act);
        float a2g = dpp_xor2(act);
        float a3g = dpp_xor2(a1g);
        float ig = (ks & 1) ? (a1g * a3g) : (act * a2g);
        float fv = sel4(a1g, act, a3g, a2g, ks);
        float ov = sel4(a3g, a2g, a1g, act, ks);

        creg = __builtin_fmaf(fv, creg, ig);
        float e2 = __builtin_amdgcn_exp2f(-(creg * (2.f * LOG2E)));
        float y2 = __builtin_amdgcn_rcpf(1.f + e2);
        float th = __builtin_fmaf(2.f, y2, -1.f);
        h = ov * th;

        if (writer) {
            hbuf[((ti + 1) & 1) * 64 + u] = h;
            if (hstr) hstr[(size_t)ti * 64 + u] = h;
            if (hl && (c * CH + ti == NT - 1)) hl[b * 64 + u] = h;
        }
        asm volatile("s_waitcnt lgkmcnt(0)" ::: "memory");
        __builtin_amdgcn_s_barrier();
        __builtin_amdgcn_sched_barrier(0);
    }
    if (writer) { STh[b * 64 + u] = h; STc[b * 64 + u] = creg; }
}

// ---------------------------------------------------------------------------
// Stage kernel: 6 roles x 256 blocks. Stage k (stream-serialized):
//  role 0: gemm0 chunk k      x -> XIN0        role 1: scan0 chunk k-1
//  role 2: gemm1 chunk k-2    H0 -> XIN1       role 3: scan1 chunk k-3
//  role 4: gemm2 chunk k-4    H1 -> XIN2       role 5: scan2 chunk k-5
// Ring buffers (4 slots) carry chunk data between stages; no atomics.
// ---------------------------------------------------------------------------
__global__ __launch_bounds__(256) void stage_kernel(
    int k, const float* __restrict__ x,
    const float* __restrict__ Wt0, const float* __restrict__ bi0, const float* __restrict__ bh0,
    const float* __restrict__ Whh0,
    const float* __restrict__ Wt1, const float* __restrict__ bi1, const float* __restrict__ bh1,
    const float* __restrict__ Whh1,
    const float* __restrict__ Wt2, const float* __restrict__ bi2, const float* __restrict__ bh2,
    const float* __restrict__ Whh2,
    float* __restrict__ XIN0, float* __restrict__ XIN1, float* __restrict__ XIN2,
    float* __restrict__ H0, float* __restrict__ H1,
    float* __restrict__ STh, float* __restrict__ STc,
    float* __restrict__ hl)
{
    __shared__ __align__(16) float smem[6656];
    const int role = blockIdx.x >> 8;
    const int b = blockIdx.x & 255;
    const int t = threadIdx.x;
    const int ks = t & 3, u = t >> 2;

    if (role == 0) {
        int c = k; if (c >= NC) return;
        gemm_role<128>(x + ((size_t)b * NT + c * CH) * 128, Wt0, bi0, bh0,
                       XIN0 + ((size_t)(c & 3) * NB + b) * (CH * 256), smem, t);
    } else if (role == 1) {
        int c = k - 1; if ((unsigned)c >= NC) return;
        scan_role(XIN0 + ((size_t)(c & 3) * NB + b) * (CH * 256) + (ks * 64 + u),
                  Whh0, H0 + ((size_t)(c & 3) * NB + b) * (CH * 64), nullptr,
                  STh + 0 * NB * 64, STc + 0 * NB * 64, b, c, t, smem);
    } else if (role == 2) {
        int c = k - 2; if ((unsigned)c >= NC) return;
        gemm_role<64>(H0 + ((size_t)(c & 3) * NB + b) * (CH * 64), Wt1, bi1, bh1,
                      XIN1 + ((size_t)(c & 3) * NB + b) * (CH * 256), smem, t);
    } else if (role == 3) {
        int c = k - 3; if ((unsigned)c >= NC) return;
        scan_role(XIN1 + ((size_t)(c & 3) * NB + b) * (CH * 256) + (ks * 64 + u),
                  Whh1, H1 + ((size_t)(c & 3) * NB + b) * (CH * 64), nullptr,
                  STh + 1 * NB * 64, STc + 1 * NB * 64, b, c, t, smem);
    } else if (role == 4) {
        int c = k - 4; if ((unsigned)c >= NC) return;
        gemm_role<64>(H1 + ((size_t)(c & 3) * NB + b) * (CH * 64), Wt2, bi2, bh2,
                      XIN2 + ((size_t)(c & 3) * NB + b) * (CH * 256), smem, t);
    } else {
        int c = k - 5; if ((unsigned)c >= NC) return;
        scan_role(XIN2 + ((size_t)(c & 3) * NB + b) * (CH * 256) + (ks * 64 + u),
                  Whh2, nullptr, hl,
                  STh + 2 * NB * 64, STc + 2 * NB * 64, b, c, t, smem);
    }
}

// ---------------------------------------------------------------------------
// Final linear: out[b][o] = b_out[o] + sum_j h_last[b][j] * W_out[o][j]
// ---------------------------------------------------------------------------
__global__ __launch_bounds__(256) void final_linear(
    const float* __restrict__ hlv, const float* __restrict__ Wout,
    const float* __restrict__ bout, float* __restrict__ out)
{
    __shared__ float w[128];
    int t = threadIdx.x;
    if (t < 128) w[t] = Wout[t];
    __syncthreads();
    const float* h = hlv + (size_t)t * 64;
    float a0 = bout[0], a1 = bout[1];
    #pragma unroll 8
    for (int j = 0; j < 64; ++j) {
        float hv = h[j];
        a0 += hv * w[j];
        a1 += hv * w[64 + j];
    }
    out[t * 2 + 0] = a0;
    out[t * 2 + 1] = a1;
}

// ---------------------------------------------------------------------------
extern "C" void kernel_launch(void* const* d_in, const int* in_sizes, int n_in,
                              void* d_out, int out_size, void* d_ws, size_t ws_size,
                              hipStream_t stream)
{
    const float* x     = (const float*)d_in[0];
    const float* W_ih0 = (const float*)d_in[1];
    const float* W_hh0 = (const float*)d_in[2];
    const float* b_ih0 = (const float*)d_in[3];
    const float* b_hh0 = (const float*)d_in[4];
    const float* W_ih1 = (const float*)d_in[5];
    const float* W_hh1 = (const float*)d_in[6];
    const float* b_ih1 = (const float*)d_in[7];
    const float* b_hh1 = (const float*)d_in[8];
    const float* W_ih2 = (const float*)d_in[9];
    const float* W_hh2 = (const float*)d_in[10];
    const float* b_ih2 = (const float*)d_in[11];
    const float* b_hh2 = (const float*)d_in[12];
    const float* W_out = (const float*)d_in[13];
    const float* b_out = (const float*)d_in[14];
    float* out = (float*)d_out;

    // workspace carve (floats)
    const size_t XINW = (size_t)4 * NB * CH * 256;   // 8.39M f each
    const size_t HW   = (size_t)4 * NB * CH * 64;    // 2.10M f each
    const size_t WT0W = 128 * 256, WT12W = 64 * 256;
    const size_t STW  = (size_t)3 * NB * 64;
    const size_t HLW  = (size_t)NB * 64;
    const size_t TOTAL_F = 3 * XINW + 2 * HW + WT0W + 2 * WT12W + 2 * STW + HLW;
    if (ws_size < TOTAL_F * sizeof(float)) return;

    float* p = (float*)d_ws;
    float* XIN0 = p; p += XINW;
    float* XIN1 = p; p += XINW;
    float* XIN2 = p; p += XINW;
    float* H0   = p; p += HW;
    float* H1   = p; p += HW;
    float* WT0  = p; p += WT0W;
    float* WT1  = p; p += WT12W;
    float* WT2  = p; p += WT12W;
    float* STh  = p; p += STW;
    float* STc  = p; p += STW;
    float* HL   = p; p += HLW;

    transpose_w<<<128, 256, 0, stream>>>(W_ih0, WT0, 128);
    transpose_w<<<64, 256, 0, stream>>>(W_ih1, WT1, 64);
    transpose_w<<<64, 256, 0, stream>>>(W_ih2, WT2, 64);

    for (int k = 0; k < NSTAGE; ++k) {
        stage_kernel<<<6 * NB, 256, 0, stream>>>(
            k, x,
            WT0, b_ih0, b_hh0, W_hh0,
            WT1, b_ih1, b_hh1, W_hh1,
            WT2, b_ih2, b_hh2, W_hh2,
            XIN0, XIN1, XIN2, H0, H1, STh, STc, HL);
    }

    final_linear<<<1, 256, 0, stream>>>(HL, W_out, b_out, out);
}

// Round 12
// 499.972 us; speedup vs baseline: 1.8961x; 1.4211x over previous
//
#include <hip/hip_runtime.h>
#include <cstddef>
#include <cstdint>

// Problem constants (from reference): B=256, T=512, I=128, H=64, 4H=256.
#define NB 256
#define NT 512
#define H4 256

typedef _Float16 v2h __attribute__((ext_vector_type(2)));

// Quad-lane exchange via DPP quad_perm (pure VALU):
// xor1: perm(1,0,3,2)=0xB1 ; xor2: perm(2,3,0,1)=0x4E
__device__ __forceinline__ float dpp_xor1(float x) {
    int r = __builtin_amdgcn_update_dpp(0, __float_as_int(x), 0xB1, 0xF, 0xF, true);
    return __int_as_float(r);
}
__device__ __forceinline__ float dpp_xor2(float x) {
    int r = __builtin_amdgcn_update_dpp(0, __float_as_int(x), 0x4E, 0xF, 0xF, true);
    return __int_as_float(r);
}
__device__ __forceinline__ float sel4(float x0, float x1, float x2, float x3, int m) {
    float lo = (m & 1) ? x1 : x0;
    float hi = (m & 1) ? x3 : x2;
    return (m & 2) ? hi : lo;
}
__device__ __forceinline__ int pack2h(float a, float b) {
    v2h p; p.x = (_Float16)a; p.y = (_Float16)b;
    return __builtin_bit_cast(int, p);
}
#if __has_builtin(__builtin_amdgcn_fdot2)
__device__ __forceinline__ float dot2acc(int wb, int xb, float c) {
    return __builtin_amdgcn_fdot2(__builtin_bit_cast(v2h, wb),
                                  __builtin_bit_cast(v2h, xb), c, false);
}
#else
__device__ __forceinline__ float dot2acc(int wb, int xb, float c) {
    v2h w = __builtin_bit_cast(v2h, wb);
    v2h x = __builtin_bit_cast(v2h, xb);
    c = __builtin_fmaf((float)w.x, (float)x.x, c);
    c = __builtin_fmaf((float)w.y, (float)x.y, c);
    return c;
}
#endif

// ---------------------------------------------------------------------------
// Transpose W [256, K] -> Wt [K, 256] (layer-0 GEMM only)
// ---------------------------------------------------------------------------
__global__ void transpose_w(const float* __restrict__ W, float* __restrict__ Wt, int K) {
    int idx = blockIdx.x * 256 + threadIdx.x;
    if (idx < 256 * K) {
        int n = idx / K, k = idx - n * K;
        Wt[k * 256 + n] = W[idx];
    }
}

// ---------------------------------------------------------------------------
// Input-projection GEMM for layer 0 only (K=128). Proven (round 1).
// ---------------------------------------------------------------------------
template <int K>
__global__ __launch_bounds__(256) void gemm_xp(
    const float* __restrict__ X, const float* __restrict__ Wt,
    const float* __restrict__ b1, const float* __restrict__ b2,
    float* __restrict__ XP)
{
    constexpr int TM = 64;
    constexpr int KC = 16;
    __shared__ __align__(16) float xT[K][TM + 4];
    __shared__ __align__(16) float wc[KC][256];
    const int m0 = blockIdx.x * TM;
    const int t  = threadIdx.x;
    const int cg = (t & 63) * 4;
    const int rg = (t >> 6) * 16;

    for (int idx = t; idx < TM * K; idx += 256) {
        int r = idx / K, k = idx - r * K;
        xT[k][r] = X[(size_t)(m0 + r) * K + k];
    }

    float acc[16][4];
    #pragma unroll
    for (int i = 0; i < 16; ++i)
        #pragma unroll
        for (int j = 0; j < 4; ++j) acc[i][j] = 0.f;

    for (int kc = 0; kc < K; kc += KC) {
        __syncthreads();
        #pragma unroll
        for (int i = 0; i < 4; ++i) {
            int e4 = (t + i * 256) * 4;
            int k = e4 >> 8, n = e4 & 255;
            *(float4*)&wc[k][n] = *(const float4*)&Wt[(size_t)(kc + k) * 256 + n];
        }
        __syncthreads();
        #pragma unroll
        for (int k = 0; k < KC; ++k) {
            float4 w = *(const float4*)&wc[k][cg];
            float xr[16];
            #pragma unroll
            for (int q = 0; q < 4; ++q)
                *(float4*)&xr[q * 4] = *(const float4*)&xT[kc + k][rg + q * 4];
            #pragma unroll
            for (int rr = 0; rr < 16; ++rr) {
                acc[rr][0] += xr[rr] * w.x;
                acc[rr][1] += xr[rr] * w.y;
                acc[rr][2] += xr[rr] * w.z;
                acc[rr][3] += xr[rr] * w.w;
            }
        }
    }

    float bias[4];
    #pragma unroll
    for (int j = 0; j < 4; ++j) bias[j] = b1[cg + j] + b2[cg + j];
    #pragma unroll
    for (int rr = 0; rr < 16; ++rr) {
        float4 o;
        o.x = acc[rr][0] + bias[0];
        o.y = acc[rr][1] + bias[1];
        o.z = acc[rr][2] + bias[2];
        o.w = acc[rr][3] + bias[3];
        *(float4*)&XP[(size_t)(m0 + rg + rr) * 256 + cg] = o;
    }
}

// ---------------------------------------------------------------------------
// Fused 3-layer wavefront-pipelined LSTM scan (round-9 structure).
// KEY FIX vs rounds 6-9: a 90112-byte LDS block forces 1 block/CU, making
// >12 waves/CU physically impossible -> the backend's achievable occupancy
// is 3 waves/EU -> register budget 512/3 = 168 BY CONSTRUCTION (attributes
// only set a minimum the compiler may exceed; LDS is a hard limit). The
// f16-packed weight file (64 int regs) + temps (~100 total) now fits, so no
// sinking (round 6: 84-cap refetch) and no spill (round 9: pinned spill).
// ---------------------------------------------------------------------------
__global__ __attribute__((amdgpu_flat_work_group_size(768, 768)))
__attribute__((amdgpu_waves_per_eu(3, 3)))
void lstm_fused3(
    const float* __restrict__ xp,    // [B*T, 256] layer-0 xp (incl. both biases)
    const float* __restrict__ Whh0,
    const float* __restrict__ Wih1, const float* __restrict__ Whh1,
    const float* __restrict__ bi1, const float* __restrict__ bh1,
    const float* __restrict__ Wih2, const float* __restrict__ Whh2,
    const float* __restrict__ bi2, const float* __restrict__ bh2,
    float* __restrict__ hl)          // [B, 64] layer-2 h at t = NT-1
{
    const int tid = threadIdx.x;
    const int b = blockIdx.x;
    const int L = tid >> 8;            // 0,1,2 (4 waves each)
    const int t256 = tid & 255;
    const int ks = t256 & 3;
    const int u = t256 >> 2;           // 0..63

    // 90112 B LDS: occupancy clamp (160 KiB/CU -> exactly 1 block/CU).
    // Only the first 768 B (hb[3][2][64] f16) are actually used.
    __shared__ __align__(16) char lds_force[90112];
    _Float16 (*hb)[2][64] = (_Float16 (*)[2][64])lds_force;

    // Recurrent weights, XOR-permuted: slot j = gate (ks^j), k-slice ks.
    // Packed f16x2 in int regs (32 regs).
    const float* Whh = (L == 0) ? Whh0 : (L == 1) ? Whh1 : Whh2;
    int wgb[4][8];
    #pragma unroll
    for (int j = 0; j < 4; ++j) {
        const float* Wr = Whh + (size_t)(((ks ^ j) * 64) + u) * 64 + ks * 16;
        #pragma unroll
        for (int q = 0; q < 8; ++q) wgb[j][q] = pack2h(Wr[2 * q], Wr[2 * q + 1]);
    }
    // Input-projection weights + bias for layers 1,2 (32 more regs)
    int wib[4][8];
    float bsum = 0.f;
    if (L > 0) {
        const float* Wih = (L == 1) ? Wih1 : Wih2;
        #pragma unroll
        for (int j = 0; j < 4; ++j) {
            const float* Wr = Wih + (size_t)(((ks ^ j) * 64) + u) * 64 + ks * 16;
            #pragma unroll
            for (int q = 0; q < 8; ++q) wib[j][q] = pack2h(Wr[2 * q], Wr[2 * q + 1]);
        }
        const float* bi = (L == 1) ? bi1 : bi2;
        const float* bh = (L == 1) ? bh1 : bh2;
        bsum = bi[ks * 64 + u] + bh[ks * 64 + u];
    }

    // Per-lane activation constants (gate 2 = tanh)
    const float LOG2E = 1.4426950408889634f;
    const float M = (ks == 2) ? (2.f * LOG2E) : LOG2E;
    const float A = (ks == 2) ? 2.f : 1.f;
    const float Bc = (ks == 2) ? -1.f : 0.f;

    if (tid < 192) ((int*)lds_force)[tid] = 0;   // zero all h buffers (768 B)

    // layer-0 xp prefetch ring (depth 4)
    const float* xpb = xp + (size_t)b * NT * H4 + (ks * 64 + u);
    float xr[4];
    if (L == 0) {
        #pragma unroll
        for (int d = 0; d < 4; ++d) xr[d] = xpb[(size_t)d * H4];
    }

    asm volatile("s_waitcnt lgkmcnt(0)" ::: "memory");
    __builtin_amdgcn_s_barrier();
    __builtin_amdgcn_sched_barrier(0);

    float c = 0.f, h = 0.f;
    const bool writer = (ks == 0);

    for (int s = 0; s < NT + 2; ++s) {
        const int t = s - L;
        const bool active = (t >= 0) && (t < NT);
        if (active) {
            // ---- own-h matvec over k-slice ks (16 f16 = 8 int reads) ----
            const int* hv = (const int*)&hb[L][t & 1][ks * 16];
            int hh[8];
            #pragma unroll
            for (int q = 0; q < 8; ++q) hh[q] = hv[q];
            float p[4];
            #pragma unroll
            for (int j = 0; j < 4; ++j) {
                float a0 = 0.f, a1 = 0.f;
                #pragma unroll
                for (int q = 0; q < 8; q += 2) {
                    a0 = dot2acc(wgb[j][q], hh[q], a0);
                    a1 = dot2acc(wgb[j][q + 1], hh[q + 1], a1);
                }
                p[j] = a0 + a1;
            }

            float xc;
            if (L == 0) {
                xc = xr[t & 3];
                int tn = t + 4; if (tn > NT - 1) tn = NT - 1;
                xr[t & 3] = xpb[(size_t)tn * H4];     // fire-and-forget refill
            } else {
                // ---- fused input projection: h^{L-1}_t slice ----
                const int* gv = (const int*)&hb[L - 1][(t + 1) & 1][ks * 16];
                int gg[8];
                #pragma unroll
                for (int q = 0; q < 8; ++q) gg[q] = gv[q];
                #pragma unroll
                for (int j = 0; j < 4; ++j) {
                    float a0 = 0.f, a1 = 0.f;
                    #pragma unroll
                    for (int q = 0; q < 8; q += 2) {
                        a0 = dot2acc(wib[j][q], gg[q], a0);
                        a1 = dot2acc(wib[j][q + 1], gg[q + 1], a1);
                    }
                    p[j] += a0 + a1;
                }
                xc = bsum;
            }

            // ---- reduce-scatter: full pre-activation of OWN gate ks ----
            float S = p[0] + dpp_xor1(p[1]);
            float t3 = dpp_xor2(dpp_xor1(p[3]));
            S += dpp_xor2(p[2]) + t3;
            float pre = S + xc;

            // ---- single branchless activation chain ----
            float e = __builtin_amdgcn_exp2f(-(pre * M));
            float y = __builtin_amdgcn_rcpf(1.f + e);
            float act = __builtin_fmaf(A, y, Bc);

            // ---- allgather + gate extraction ----
            float a1g = dpp_xor1(act);
            float a2g = dpp_xor2(act);
            float a3g = dpp_xor2(a1g);
            float ig = (ks & 1) ? (a1g * a3g) : (act * a2g);   // i*g
            float fv = sel4(a1g, act, a3g, a2g, ks);           // f
            float ov = sel4(a3g, a2g, a1g, act, ks);           // o

            // ---- cell update (redundant x4, identical bits) ----
            c = __builtin_fmaf(fv, c, ig);
            float e2 = __builtin_amdgcn_exp2f(-(c * (2.f * LOG2E)));
            float y2 = __builtin_amdgcn_rcpf(1.f + e2);
            float th = __builtin_fmaf(2.f, y2, -1.f);
            h = ov * th;

            if (writer) {
                hb[L][(t + 1) & 1][u] = (_Float16)h;   // parity no reader touches
                if (L == 2 && t == NT - 1) hl[(size_t)b * 64 + u] = h;
            }
        }
        asm volatile("s_waitcnt lgkmcnt(0)" ::: "memory");
        __builtin_amdgcn_s_barrier();
        __builtin_amdgcn_sched_barrier(0);
    }
}

// ---------------------------------------------------------------------------
// Final linear: out[b][o] = b_out[o] + sum_j h_last[b][j] * W_out[o][j]
// ---------------------------------------------------------------------------
__global__ __launch_bounds__(256) void final_linear(
    const float* __restrict__ hlv, const float* __restrict__ Wout,
    const float* __restrict__ bout, float* __restrict__ out)
{
    __shared__ float w[128];
    int t = threadIdx.x;
    if (t < 128) w[t] = Wout[t];
    __syncthreads();
    const float* h = hlv + (size_t)t * 64;
    float a0 = bout[0], a1 = bout[1];
    #pragma unroll 8
    for (int j = 0; j < 64; ++j) {
        float hv = h[j];
        a0 += hv * w[j];
        a1 += hv * w[64 + j];
    }
    out[t * 2 + 0] = a0;
    out[t * 2 + 1] = a1;
}

// ---------------------------------------------------------------------------
extern "C" void kernel_launch(void* const* d_in, const int* in_sizes, int n_in,
                              void* d_out, int out_size, void* d_ws, size_t ws_size,
                              hipStream_t stream)
{
    const float* x     = (const float*)d_in[0];
    const float* W_ih0 = (const float*)d_in[1];
    const float* W_hh0 = (const float*)d_in[2];
    const float* b_ih0 = (const float*)d_in[3];
    const float* b_hh0 = (const float*)d_in[4];
    const float* W_ih1 = (const float*)d_in[5];
    const float* W_hh1 = (const float*)d_in[6];
    const float* b_ih1 = (const float*)d_in[7];
    const float* b_hh1 = (const float*)d_in[8];
    const float* W_ih2 = (const float*)d_in[9];
    const float* W_hh2 = (const float*)d_in[10];
    const float* b_ih2 = (const float*)d_in[11];
    const float* b_hh2 = (const float*)d_in[12];
    const float* W_out = (const float*)d_in[13];
    const float* b_out = (const float*)d_in[14];
    float* out = (float*)d_out;

    const size_t M = (size_t)NB * NT;                  // 131072
    const size_t XP_BYTES  = M * H4 * sizeof(float);   // 128 MiB
    const size_t WT0_BYTES = 128 * 256 * sizeof(float);
    const size_t HL_BYTES  = NB * 64 * sizeof(float);
    if (ws_size < XP_BYTES + WT0_BYTES + HL_BYTES)
        return;

    char* ws = (char*)d_ws;
    float* XP  = (float*)ws;
    float* WT0 = (float*)(ws + XP_BYTES);
    float* HL  = WT0 + 128 * 256;

    // Layer-0 input projection (parallel GEMM) — layers 1,2 are fused.
    transpose_w<<<128, 256, 0, stream>>>(W_ih0, WT0, 128);
    gemm_xp<128><<<(int)(M / 64), 256, 0, stream>>>(x, WT0, b_ih0, b_hh0, XP);

    // Fused 3-layer pipelined scan (1 block/CU enforced via LDS).
    lstm_fused3<<<NB, 768, 0, stream>>>(XP, W_hh0,
                                        W_ih1, W_hh1, b_ih1, b_hh1,
                                        W_ih2, W_hh2, b_ih2, b_hh2, HL);

    // Final projection.
    final_linear<<<1, 256, 0, stream>>>(HL, W_out, b_out, out);
}